// Round 1
// baseline (19291.678 us; speedup 1.0000x reference)
//
#include <hip/hip_runtime.h>
#include <math.h>

// Problem constants (shapes derived at launch from in_sizes/out_size)
#define D_F   64      // feature dim
#define IN_F  183     // 2*64 + 2*25 + 3 + 1 + 1
#define XPAD  184     // padded x row stride in LDS
#define HID   256
#define H1PAD 257     // padded h1 row stride in LDS (breaks bank alignment)
#define BM    64      // rows (jobs) per block

// ---------------------------------------------------------------------------
// Fused MLP kernel: one "job" = one MLP row = (t, k, e).
//   t=0 : k=0 only, E jobs  -> p0 broadcast to all 3 rows of cond[0,e,:,:]
//   t>=1: 3E jobs per t     -> cond[t,e,k,:]
// ---------------------------------------------------------------------------
__global__ __launch_bounds__(256, 2)
void mfp_mlp_kernel(const float* __restrict__ features,
                    const float* __restrict__ states,
                    const float* __restrict__ distances,
                    const float* __restrict__ W1, const float* __restrict__ b1,
                    const float* __restrict__ W2, const float* __restrict__ b2,
                    const float* __restrict__ W3, const float* __restrict__ b3,
                    const int* __restrict__ pairs_i,
                    const int* __restrict__ pairs_j,
                    float* __restrict__ cond,   // (T+1, E, 3, 3)
                    int N, int T1s, int E, int T)
{
    extern __shared__ float buf[];   // union: x[BM][XPAD] then h1[BM][H1PAD]
    __shared__ int s_pi[BM], s_pj[BM], s_t[BM], s_k[BM], s_e[BM], s_val[BM];

    const int tid = threadIdx.x;
    const long long J  = (long long)E * (1 + 3 * T);
    const long long j0 = (long long)blockIdx.x * BM;

    // ---- per-row meta ----
    if (tid < BM) {
        long long j = j0 + tid;
        int valid = (j < J) ? 1 : 0;
        long long jj = valid ? j : 0;
        int t, k, e;
        if (jj < E) { t = 0; k = 0; e = (int)jj; }
        else {
            long long q = jj - E;
            t = 1 + (int)(q / (3LL * E));
            long long r = q - (long long)(t - 1) * (3LL * E);
            k = (int)(r / E);
            e = (int)(r - (long long)k * E);
        }
        s_t[tid] = t; s_k[tid] = k; s_e[tid] = e; s_val[tid] = valid;
        s_pi[tid] = pairs_i[e];
        s_pj[tid] = pairs_j[e];
    }
    __syncthreads();

    // ---- assemble x rows into LDS ----
    // x = [fi(64) | fj(64) | hist_i(25) | hist_j(25) | onehot_k(3) | dist(1) | (t==0)(1)]
    // hist[t,n,l*5+s] = (t-4+l >= 0) ? states[n, t-4+l, s] : 0
    for (int idx = tid; idx < BM * IN_F; idx += 256) {
        int m = idx / IN_F;
        int c = idx - m * IN_F;
        int pi = s_pi[m], pj = s_pj[m], t = s_t[m];
        float v;
        if (c < 64) {
            v = features[pi * D_F + c];
        } else if (c < 128) {
            v = features[pj * D_F + (c - 64)];
        } else if (c < 178) {
            int cc = c - 128;
            int row = (cc < 25) ? pi : pj;
            int c2  = (cc < 25) ? cc : (cc - 25);
            int l = c2 / 5;
            int s = c2 - l * 5;
            int tau = t - 4 + l;
            v = (tau >= 0) ? states[(row * T1s + tau) * 5 + s] : 0.0f;
        } else if (c < 181) {
            v = ((c - 178) == s_k[m]) ? 1.0f : 0.0f;
        } else if (c == 181) {
            v = distances[(long long)pi * N + pj];
        } else {
            v = (t == 0) ? 1.0f : 0.0f;
        }
        buf[m * XPAD + c] = v;
    }
    __syncthreads();

    const int cg = tid & 15;    // column group: cols [cg*16, cg*16+16)
    const int rg = tid >> 4;    // row group:    rows [rg*4,  rg*4+4)
    const int c0 = cg * 16;
    const int r0 = rg * 4;

    // ---- layer 1: h1 = relu(x @ W1 + b1) ----
    float acc[4][16];
    #pragma unroll
    for (int i = 0; i < 4; ++i)
        #pragma unroll
        for (int j = 0; j < 16; ++j)
            acc[i][j] = b1[c0 + j];

    for (int kk = 0; kk < IN_F; ++kk) {
        float xv[4];
        #pragma unroll
        for (int i = 0; i < 4; ++i) xv[i] = buf[(r0 + i) * XPAD + kk];
        const float* wr = &W1[kk * HID + c0];
        float4 w0 = *(const float4*)(wr + 0);
        float4 w1 = *(const float4*)(wr + 4);
        float4 w2 = *(const float4*)(wr + 8);
        float4 w3 = *(const float4*)(wr + 12);
        float w[16] = { w0.x, w0.y, w0.z, w0.w, w1.x, w1.y, w1.z, w1.w,
                        w2.x, w2.y, w2.z, w2.w, w3.x, w3.y, w3.z, w3.w };
        #pragma unroll
        for (int i = 0; i < 4; ++i)
            #pragma unroll
            for (int j = 0; j < 16; ++j)
                acc[i][j] = fmaf(xv[i], w[j], acc[i][j]);
    }

    __syncthreads();   // all x reads done; safe to overwrite buf with h1
    #pragma unroll
    for (int i = 0; i < 4; ++i)
        #pragma unroll
        for (int j = 0; j < 16; ++j)
            buf[(r0 + i) * H1PAD + c0 + j] = fmaxf(acc[i][j], 0.0f);
    __syncthreads();

    // ---- layer 2: h2 = relu(h1 @ W2 + b2) ----
    #pragma unroll
    for (int i = 0; i < 4; ++i)
        #pragma unroll
        for (int j = 0; j < 16; ++j)
            acc[i][j] = b2[c0 + j];

    for (int kk = 0; kk < HID; ++kk) {
        float xv[4];
        #pragma unroll
        for (int i = 0; i < 4; ++i) xv[i] = buf[(r0 + i) * H1PAD + kk];
        const float* wr = &W2[kk * HID + c0];
        float4 w0 = *(const float4*)(wr + 0);
        float4 w1 = *(const float4*)(wr + 4);
        float4 w2 = *(const float4*)(wr + 8);
        float4 w3 = *(const float4*)(wr + 12);
        float w[16] = { w0.x, w0.y, w0.z, w0.w, w1.x, w1.y, w1.z, w1.w,
                        w2.x, w2.y, w2.z, w2.w, w3.x, w3.y, w3.z, w3.w };
        #pragma unroll
        for (int i = 0; i < 4; ++i)
            #pragma unroll
            for (int j = 0; j < 16; ++j)
                acc[i][j] = fmaf(xv[i], w[j], acc[i][j]);
    }

    // ---- layer 3: logits = h2 @ W3 + b3 (partial per thread, reduce over cg) ----
    float part[4][3];
    #pragma unroll
    for (int i = 0; i < 4; ++i)
        #pragma unroll
        for (int n = 0; n < 3; ++n)
            part[i][n] = 0.0f;

    #pragma unroll
    for (int j = 0; j < 16; ++j) {
        int c = c0 + j;
        float w30 = W3[c * 3 + 0];
        float w31 = W3[c * 3 + 1];
        float w32 = W3[c * 3 + 2];
        #pragma unroll
        for (int i = 0; i < 4; ++i) {
            float h = fmaxf(acc[i][j], 0.0f);
            part[i][0] = fmaf(h, w30, part[i][0]);
            part[i][1] = fmaf(h, w31, part[i][1]);
            part[i][2] = fmaf(h, w32, part[i][2]);
        }
    }

    // butterfly reduce across the 16 col-groups (contiguous 16 lanes per rg)
    #pragma unroll
    for (int off = 1; off < 16; off <<= 1) {
        #pragma unroll
        for (int i = 0; i < 4; ++i) {
            part[i][0] += __shfl_xor(part[i][0], off, 64);
            part[i][1] += __shfl_xor(part[i][1], off, 64);
            part[i][2] += __shfl_xor(part[i][2], off, 64);
        }
    }

    // ---- softmax + write ----
    if (cg == 0) {
        #pragma unroll
        for (int i = 0; i < 4; ++i) {
            int m = r0 + i;
            if (!s_val[m]) continue;
            float l0 = part[i][0] + b3[0];
            float l1 = part[i][1] + b3[1];
            float l2 = part[i][2] + b3[2];
            float mx = fmaxf(l0, fmaxf(l1, l2));
            float e0 = expf(l0 - mx), e1 = expf(l1 - mx), e2 = expf(l2 - mx);
            float inv = 1.0f / (e0 + e1 + e2);
            float p0 = e0 * inv, p1 = e1 * inv, p2 = e2 * inv;
            int t = s_t[m], k = s_k[m], e = s_e[m];
            size_t base = ((size_t)t * E + e) * 9;
            if (t == 0) {
                #pragma unroll
                for (int kb = 0; kb < 3; ++kb) {
                    cond[base + kb * 3 + 0] = p0;
                    cond[base + kb * 3 + 1] = p1;
                    cond[base + kb * 3 + 2] = p2;
                }
            } else {
                cond[base + k * 3 + 0] = p0;
                cond[base + k * 3 + 1] = p1;
                cond[base + k * 3 + 2] = p2;
            }
        }
    }
}

// ---------------------------------------------------------------------------
// Marginal chain: m_t = m_{t-1} @ cond[t]  (cheap, sequential over t)
// ---------------------------------------------------------------------------
__global__ __launch_bounds__(256)
void mfp_marg_kernel(const float* __restrict__ cond,
                     float* __restrict__ marg,
                     int E, int T)
{
    int e = blockIdx.x * 256 + threadIdx.x;
    if (e >= E) return;
    // m0 = p0 = cond[0, e, 0, :]
    const float* c0 = &cond[(size_t)e * 9];
    float m0 = c0[0], m1 = c0[1], m2 = c0[2];
    marg[(size_t)e * 3 + 0] = m0;
    marg[(size_t)e * 3 + 1] = m1;
    marg[(size_t)e * 3 + 2] = m2;
    for (int t = 1; t <= T; ++t) {
        const float* c9 = &cond[((size_t)t * E + e) * 9];
        float n0 = m0 * c9[0] + m1 * c9[3] + m2 * c9[6];
        float n1 = m0 * c9[1] + m1 * c9[4] + m2 * c9[7];
        float n2 = m0 * c9[2] + m1 * c9[5] + m2 * c9[8];
        m0 = n0; m1 = n1; m2 = n2;
        float* mo = &marg[((size_t)t * E + e) * 3];
        mo[0] = m0; mo[1] = m1; mo[2] = m2;
    }
}

// ---------------------------------------------------------------------------
extern "C" void kernel_launch(void* const* d_in, const int* in_sizes, int n_in,
                              void* d_out, int out_size, void* d_ws, size_t ws_size,
                              hipStream_t stream) {
    const float* features  = (const float*)d_in[0];
    const float* states    = (const float*)d_in[1];
    const float* distances = (const float*)d_in[2];
    const float* W1 = (const float*)d_in[3];
    const float* b1 = (const float*)d_in[4];
    const float* W2 = (const float*)d_in[5];
    const float* b2 = (const float*)d_in[6];
    const float* W3 = (const float*)d_in[7];
    const float* b3 = (const float*)d_in[8];
    const int* pairs_i = (const int*)d_in[9];
    const int* pairs_j = (const int*)d_in[10];

    const int N   = in_sizes[0] / D_F;             // 2000
    const int T1s = in_sizes[1] / (N * 5);         // 11
    const int E   = in_sizes[9];                   // 100000
    const int T   = out_size / (12 * E) - 1;       // 10  (out = 12*E*(T+1))

    float* cond = (float*)d_out;                            // (T+1, E, 3, 3)
    float* marg = (float*)d_out + (size_t)(T + 1) * E * 9;  // (T+1, E, 3)

    const long long J = (long long)E * (1 + 3 * T);
    const int nblocks = (int)((J + BM - 1) / BM);
    const size_t lds_bytes = (size_t)BM * H1PAD * sizeof(float);

    mfp_mlp_kernel<<<nblocks, 256, lds_bytes, stream>>>(
        features, states, distances, W1, b1, W2, b2, W3, b3,
        pairs_i, pairs_j, cond, N, T1s, E, T);

    mfp_marg_kernel<<<(E + 255) / 256, 256, 0, stream>>>(cond, marg, E, T);
}

// Round 3
// 1101.829 us; speedup vs baseline: 17.5088x; 17.5088x over previous
//
#include <hip/hip_runtime.h>
#include <hip/hip_bf16.h>
#include <math.h>

#define D_F   64
#define IN_F  183     // 2*64 + 2*25 + 3 + 1 + 1
#define KS1   6       // layer-1 K tiles: 192 = 6*32 (padded from 183)
#define KS2   8       // layer-2 K tiles: 256 = 8*32
#define HID   256
#define XPITCH 200    // u16 per x row: 400B = 25 x 16B, 25%8==1 -> uniform bank spread
#define HPITCH 264    // u16 per h row: 528B = 33 x 16B, 33%8==1
#define BM    64      // jobs per block

typedef unsigned short u16;
typedef __attribute__((ext_vector_type(8))) short bf16x8;
typedef __attribute__((ext_vector_type(4))) float f32x4;

__device__ __forceinline__ u16 f2bf(float v) {
    __hip_bfloat16 h = __float2bfloat16(v);   // RNE
    u16 u; __builtin_memcpy(&u, &h, 2); return u;
}

// ---------------------------------------------------------------------------
// Pack W (K x 256 f32, row-major) into MFMA B-fragment order (bf16):
//   Wp[((ct*KSs + ks)*64 + lane)*8 + j] = W[ks*32 + 8*(lane>>4) + j][ct*16 + (lane&15)]
// ---------------------------------------------------------------------------
__global__ void pack_w_kernel(const float* __restrict__ W, u16* __restrict__ Wp,
                              int K, int KSs)
{
    int g = blockIdx.x * 256 + threadIdx.x;
    int total = 16 * KSs * 64;
    if (g >= total) return;
    int lane = g & 63;
    int ks   = (g >> 6) % KSs;
    int ct   = (g >> 6) / KSs;
    int col  = ct * 16 + (lane & 15);
    int kb   = ks * 32 + 8 * (lane >> 4);
    u16 out[8];
    #pragma unroll
    for (int j = 0; j < 8; ++j) {
        int k = kb + j;
        out[j] = f2bf((k < K) ? W[(size_t)k * HID + col] : 0.0f);
    }
    u16* dst = Wp + (size_t)g * 8;
    *(bf16x8*)dst = *(const bf16x8*)out;
}

// ---------------------------------------------------------------------------
// Fused MFMA MLP. One job = one MLP row = (t,k,e); 64 jobs/block, 4 waves.
// Wave w computes cols [64w, 64w+64) of both hidden layers; layer-3 partials
// are reduced in-wave (split butterfly) then cross-wave via LDS.
// ---------------------------------------------------------------------------
__global__ __launch_bounds__(256, 2)
void mfp_mlp_mfma(const float* __restrict__ features,
                  const float* __restrict__ states,
                  const float* __restrict__ distances,
                  const u16* __restrict__ W1p, const float* __restrict__ b1,
                  const u16* __restrict__ W2p, const float* __restrict__ b2,
                  const float* __restrict__ W3, const float* __restrict__ b3,
                  const int* __restrict__ pairs_i, const int* __restrict__ pairs_j,
                  float* __restrict__ cond,
                  int N, int T1s, int E, int T)
{
    extern __shared__ char smem[];
    u16* xs = (u16*)smem;   // [64][XPITCH]  (layer-1 A)
    u16* hs = (u16*)smem;   // [64][HPITCH]  (layer-2 A, union after sync)
    __shared__ int   s_pi[BM], s_pj[BM], s_t[BM], s_k[BM], s_e[BM], s_val[BM];
    __shared__ float s_dist[BM];
    __shared__ float s_plog[4][BM][3];   // per-wave partial logits

    const int tid = threadIdx.x;
    const long long J  = (long long)E * (1 + 3 * T);
    const long long j0 = (long long)blockIdx.x * BM;

    // ---- per-job meta ----
    if (tid < BM) {
        long long j = j0 + tid;
        int valid = (j < J) ? 1 : 0;
        long long jj = valid ? j : 0;
        int t, k, e;
        if (jj < E) { t = 0; k = 0; e = (int)jj; }
        else {
            long long q = jj - E;
            t = 1 + (int)(q / (3LL * E));
            long long r = q - (long long)(t - 1) * (3LL * E);
            k = (int)(r / E);
            e = (int)(r - (long long)k * E);
        }
        int pi = pairs_i[e], pj = pairs_j[e];
        s_t[tid] = t; s_k[tid] = k; s_e[tid] = e; s_val[tid] = valid;
        s_pi[tid] = pi; s_pj[tid] = pj;
        s_dist[tid] = distances[(long long)pi * N + pj];
    }
    __syncthreads();

    // ---- assemble x rows (bf16) ----
    for (int idx = tid; idx < BM * 32; idx += 256) {     // cols 0..127: features
        int m = idx >> 5;
        int q = idx & 31;
        int src = (q < 16) ? s_pi[m] : s_pj[m];
        int c4  = (q & 15) * 4;
        float4 f = *(const float4*)&features[(size_t)src * D_F + c4];
        int c = ((q < 16) ? 0 : 64) + c4;
        ushort4 o;
        o.x = f2bf(f.x); o.y = f2bf(f.y); o.z = f2bf(f.z); o.w = f2bf(f.w);
        *(ushort4*)(xs + m * XPITCH + c) = o;
    }
    for (int idx = tid; idx < BM * 64; idx += 256) {     // cols 128..191
        int m = idx >> 6;
        int c = 128 + (idx & 63);
        int t = s_t[m];
        float v;
        if (c < 178) {
            int cc = c - 128;
            int row = (cc < 25) ? s_pi[m] : s_pj[m];
            int c2  = (cc < 25) ? cc : (cc - 25);
            int l = c2 / 5;
            int s = c2 - l * 5;
            int tau = t - 4 + l;
            v = (tau >= 0) ? states[((size_t)row * T1s + tau) * 5 + s] : 0.0f;
        } else if (c < 181) {
            v = ((c - 178) == s_k[m]) ? 1.0f : 0.0f;
        } else if (c == 181) {
            v = s_dist[m];
        } else if (c == 182) {
            v = (t == 0) ? 1.0f : 0.0f;
        } else {
            v = 0.0f;   // pad 183..191
        }
        xs[m * XPITCH + c] = f2bf(v);
    }
    __syncthreads();

    const int lane = tid & 63;
    const int w    = tid >> 6;     // wave id 0..3
    const int ct0  = w * 4;        // col-tile base (cols 64w .. 64w+63)
    const int lr   = lane & 15;
    const int lg   = lane >> 4;

    // ---- layer 1: h1 = relu(x @ W1 + b1), MFMA ----
    f32x4 acc[4][4];
    #pragma unroll
    for (int a = 0; a < 4; ++a)
        #pragma unroll
        for (int b = 0; b < 4; ++b)
            acc[a][b] = (f32x4){0.f, 0.f, 0.f, 0.f};

    for (int ks = 0; ks < KS1; ++ks) {
        bf16x8 bfr[4];
        #pragma unroll
        for (int ctl = 0; ctl < 4; ++ctl)
            bfr[ctl] = *(const bf16x8*)(W1p + (((size_t)(ct0 + ctl) * KS1 + ks) * 64 + lane) * 8);
        bf16x8 afr[4];
        #pragma unroll
        for (int rt = 0; rt < 4; ++rt)
            afr[rt] = *(const bf16x8*)(xs + (rt * 16 + lr) * XPITCH + ks * 32 + 8 * lg);
        #pragma unroll
        for (int rt = 0; rt < 4; ++rt)
            #pragma unroll
            for (int ctl = 0; ctl < 4; ++ctl)
                acc[rt][ctl] = __builtin_amdgcn_mfma_f32_16x16x32_bf16(afr[rt], bfr[ctl], acc[rt][ctl], 0, 0, 0);
    }

    float b1v[4];
    #pragma unroll
    for (int ctl = 0; ctl < 4; ++ctl) b1v[ctl] = b1[(ct0 + ctl) * 16 + lr];

    __syncthreads();   // all x reads done; safe to overwrite with h1
    #pragma unroll
    for (int rt = 0; rt < 4; ++rt)
        #pragma unroll
        for (int ctl = 0; ctl < 4; ++ctl)
            #pragma unroll
            for (int r = 0; r < 4; ++r) {
                float h = fmaxf(acc[rt][ctl][r] + b1v[ctl], 0.0f);
                hs[(rt * 16 + 4 * lg + r) * HPITCH + (ct0 + ctl) * 16 + lr] = f2bf(h);
            }
    __syncthreads();

    // ---- layer 2: h2pre = h1 @ W2, MFMA ----
    f32x4 acc2[4][4];
    #pragma unroll
    for (int a = 0; a < 4; ++a)
        #pragma unroll
        for (int b = 0; b < 4; ++b)
            acc2[a][b] = (f32x4){0.f, 0.f, 0.f, 0.f};

    for (int ks = 0; ks < KS2; ++ks) {
        bf16x8 bfr[4];
        #pragma unroll
        for (int ctl = 0; ctl < 4; ++ctl)
            bfr[ctl] = *(const bf16x8*)(W2p + (((size_t)(ct0 + ctl) * KS2 + ks) * 64 + lane) * 8);
        bf16x8 afr[4];
        #pragma unroll
        for (int rt = 0; rt < 4; ++rt)
            afr[rt] = *(const bf16x8*)(hs + (rt * 16 + lr) * HPITCH + ks * 32 + 8 * lg);
        #pragma unroll
        for (int rt = 0; rt < 4; ++rt)
            #pragma unroll
            for (int ctl = 0; ctl < 4; ++ctl)
                acc2[rt][ctl] = __builtin_amdgcn_mfma_f32_16x16x32_bf16(afr[rt], bfr[ctl], acc2[rt][ctl], 0, 0, 0);
    }

    // ---- layer 3 (f32): per-lane partials over this wave's 64 cols ----
    float b2v[4], w3v[4][3];
    #pragma unroll
    for (int ctl = 0; ctl < 4; ++ctl) {
        int col = (ct0 + ctl) * 16 + lr;
        b2v[ctl] = b2[col];
        w3v[ctl][0] = W3[col * 3 + 0];
        w3v[ctl][1] = W3[col * 3 + 1];
        w3v[ctl][2] = W3[col * 3 + 2];
    }

    // part[v][n], v = 4*rt + r  (value for row m = 16*rt + 4*lg + r)
    float part[16][3];
    #pragma unroll
    for (int v = 0; v < 16; ++v) { part[v][0] = 0.f; part[v][1] = 0.f; part[v][2] = 0.f; }

    #pragma unroll
    for (int rt = 0; rt < 4; ++rt)
        #pragma unroll
        for (int ctl = 0; ctl < 4; ++ctl)
            #pragma unroll
            for (int r = 0; r < 4; ++r) {
                float h = fmaxf(acc2[rt][ctl][r] + b2v[ctl], 0.0f);
                int v = rt * 4 + r;
                part[v][0] = fmaf(h, w3v[ctl][0], part[v][0]);
                part[v][1] = fmaf(h, w3v[ctl][1], part[v][1]);
                part[v][2] = fmaf(h, w3v[ctl][2], part[v][2]);
            }

    // progressive split-butterfly across the 16 lanes of each lg-group:
    // after the 4 stages lane lr owns v == lr, fully reduced over the group.
    float s8[8][3];
    #pragma unroll
    for (int i = 0; i < 8; ++i)
        #pragma unroll
        for (int n = 0; n < 3; ++n) {
            float a = part[2 * i][n]     + __shfl_xor(part[2 * i][n], 1, 64);
            float b = part[2 * i + 1][n] + __shfl_xor(part[2 * i + 1][n], 1, 64);
            s8[i][n] = (lr & 1) ? b : a;
        }
    float s4[4][3];
    #pragma unroll
    for (int i = 0; i < 4; ++i)
        #pragma unroll
        for (int n = 0; n < 3; ++n) {
            float a = s8[2 * i][n]     + __shfl_xor(s8[2 * i][n], 2, 64);
            float b = s8[2 * i + 1][n] + __shfl_xor(s8[2 * i + 1][n], 2, 64);
            s4[i][n] = (lr & 2) ? b : a;
        }
    float s2[2][3];
    #pragma unroll
    for (int i = 0; i < 2; ++i)
        #pragma unroll
        for (int n = 0; n < 3; ++n) {
            float a = s4[2 * i][n]     + __shfl_xor(s4[2 * i][n], 4, 64);
            float b = s4[2 * i + 1][n] + __shfl_xor(s4[2 * i + 1][n], 4, 64);
            s2[i][n] = (lr & 4) ? b : a;
        }
    float s1[3];
    #pragma unroll
    for (int n = 0; n < 3; ++n) {
        float a = s2[0][n] + __shfl_xor(s2[0][n], 8, 64);
        float b = s2[1][n] + __shfl_xor(s2[1][n], 8, 64);
        s1[n] = (lr & 8) ? b : a;
    }

    // lane owns row m's partial over this wave's 64 cols
    {
        int m = 16 * (lr >> 2) + 4 * lg + (lr & 3);
        s_plog[w][m][0] = s1[0];
        s_plog[w][m][1] = s1[1];
        s_plog[w][m][2] = s1[2];
    }
    __syncthreads();

    // ---- cross-wave sum + softmax + write (one thread per row) ----
    if (tid < BM && s_val[tid]) {
        int m = tid;
        float l0 = s_plog[0][m][0] + s_plog[1][m][0] + s_plog[2][m][0] + s_plog[3][m][0] + b3[0];
        float l1 = s_plog[0][m][1] + s_plog[1][m][1] + s_plog[2][m][1] + s_plog[3][m][1] + b3[1];
        float l2 = s_plog[0][m][2] + s_plog[1][m][2] + s_plog[2][m][2] + s_plog[3][m][2] + b3[2];
        float mx = fmaxf(l0, fmaxf(l1, l2));
        float e0 = expf(l0 - mx), e1 = expf(l1 - mx), e2 = expf(l2 - mx);
        float inv = 1.0f / (e0 + e1 + e2);
        float p0 = e0 * inv, p1 = e1 * inv, p2 = e2 * inv;
        int t = s_t[m], k = s_k[m], e = s_e[m];
        size_t base = ((size_t)t * E + e) * 9;
        if (t == 0) {
            #pragma unroll
            for (int kb = 0; kb < 3; ++kb) {
                cond[base + kb * 3 + 0] = p0;
                cond[base + kb * 3 + 1] = p1;
                cond[base + kb * 3 + 2] = p2;
            }
        } else {
            cond[base + k * 3 + 0] = p0;
            cond[base + k * 3 + 1] = p1;
            cond[base + k * 3 + 2] = p2;
        }
    }
}

// ---------------------------------------------------------------------------
// Marginal chain: m_t = m_{t-1} @ cond[t]
// ---------------------------------------------------------------------------
__global__ __launch_bounds__(256)
void mfp_marg_kernel(const float* __restrict__ cond,
                     float* __restrict__ marg,
                     int E, int T)
{
    int e = blockIdx.x * 256 + threadIdx.x;
    if (e >= E) return;
    const float* c0 = &cond[(size_t)e * 9];
    float m0 = c0[0], m1 = c0[1], m2 = c0[2];
    marg[(size_t)e * 3 + 0] = m0;
    marg[(size_t)e * 3 + 1] = m1;
    marg[(size_t)e * 3 + 2] = m2;
    for (int t = 1; t <= T; ++t) {
        const float* c9 = &cond[((size_t)t * E + e) * 9];
        float n0 = m0 * c9[0] + m1 * c9[3] + m2 * c9[6];
        float n1 = m0 * c9[1] + m1 * c9[4] + m2 * c9[7];
        float n2 = m0 * c9[2] + m1 * c9[5] + m2 * c9[8];
        m0 = n0; m1 = n1; m2 = n2;
        float* mo = &marg[((size_t)t * E + e) * 3];
        mo[0] = m0; mo[1] = m1; mo[2] = m2;
    }
}

// ---------------------------------------------------------------------------
extern "C" void kernel_launch(void* const* d_in, const int* in_sizes, int n_in,
                              void* d_out, int out_size, void* d_ws, size_t ws_size,
                              hipStream_t stream) {
    const float* features  = (const float*)d_in[0];
    const float* states    = (const float*)d_in[1];
    const float* distances = (const float*)d_in[2];
    const float* W1 = (const float*)d_in[3];
    const float* b1 = (const float*)d_in[4];
    const float* W2 = (const float*)d_in[5];
    const float* b2 = (const float*)d_in[6];
    const float* W3 = (const float*)d_in[7];
    const float* b3 = (const float*)d_in[8];
    const int* pairs_i = (const int*)d_in[9];
    const int* pairs_j = (const int*)d_in[10];

    const int N   = in_sizes[0] / D_F;             // 2000
    const int T1s = in_sizes[1] / (N * 5);         // 11
    const int E   = in_sizes[9];                   // 100000
    const int T   = out_size / (12 * E) - 1;       // 10

    float* cond = (float*)d_out;                            // (T+1, E, 3, 3)
    float* marg = (float*)d_out + (size_t)(T + 1) * E * 9;  // (T+1, E, 3)

    u16* W1p = (u16*)d_ws;                                  // 16*KS1*64*8 elems
    u16* W2p = W1p + 16 * KS1 * 64 * 8;

    {
        int g1 = 16 * KS1 * 64;
        int g2 = 16 * KS2 * 64;
        pack_w_kernel<<<(g1 + 255) / 256, 256, 0, stream>>>(W1, W1p, IN_F, KS1);
        pack_w_kernel<<<(g2 + 255) / 256, 256, 0, stream>>>(W2, W2p, HID, KS2);
    }

    const long long J = (long long)E * (1 + 3 * T);
    const int nblocks = (int)((J + BM - 1) / BM);
    const size_t lds_bytes = (size_t)BM * HPITCH * sizeof(u16);

    mfp_mlp_mfma<<<nblocks, 256, lds_bytes, stream>>>(
        features, states, distances, W1p, b1, W2p, b2, W3, b3,
        pairs_i, pairs_j, cond, N, T1s, E, T);

    mfp_marg_kernel<<<(E + 255) / 256, 256, 0, stream>>>(cond, marg, E, T);
}